// Round 8
// baseline (264.617 us; speedup 1.0000x reference)
//
#include <hip/hip_runtime.h>

#define NF    39
#define EMB   64
#define NPAIR 741   // C(39,2)
#define RS    72    // LDS row stride in ushorts: 64 + 8 replicated tail

// LDS layout (ushort offsets). xssw at +2848 from xdsw (== 16 mod 32 banks):
// odd-lane and even-lane bank runs disjoint.
#define XD    0                 // xd[p][i]   = bf16(x[i&63])           (B-frags)
#define XDSW  2816              // xdsw[p][2j]=x[2j+1], [2j+1]=x[2j]    (A, odd c)
#define XSSW  (2816 + 2848)     // xssw[p][2j]=x[2j+2], [2j+1]=x[2j+1]  (A, even c)
#define LDSZ  (XSSW + NF * RS)  // 8472 ushorts = 16944 B

typedef short bf16x8 __attribute__((ext_vector_type(8)));
typedef float f32x4  __attribute__((ext_vector_type(4)));

union FragU { uint32_t u[4]; bf16x8 v; };

// out[b, pair(p,q), n] = sum_m x_p[(n-m)&63] * x_q[m]  (circular convolution)
// MFMA 16x16x32 bf16, D = A(circulant x_p) * B(cols x_q), C/D layout per m89.
//
// R8 = R7 + NONTEMPORAL stores. The 759MB output stream through the 32MB
// write-back L2 forces continuous allocate+evict; nt streams it (fill-kernel
// writes ~6.7 TB/s, ours was 4.5). Everything else identical to R7 (wave owns
// all 4 n-tiles of its p: full-256B-row stores; 4 shared 16B A-runs per p).
__global__ __launch_bounds__(256) void holo_mfma_kernel(
    const float* __restrict__ emb,   // [B, 39, 64]
    float* __restrict__ out)         // [B, 741, 64]
{
    __shared__ __align__(16) unsigned short lds[LDSZ];

    const int b   = blockIdx.x;
    const int tid = threadIdx.x;
    const int l   = tid & 63;
    const int w   = tid >> 6;             // wave = p-stripe index (0..3)
    const int g   = l >> 4;

    const float* __restrict__ ebase = emb + (size_t)b * (NF * EMB);
    float* __restrict__ obase = out + (size_t)b * (size_t)(NPAIR * EMB);

    // ---- stage 3 bf16 copies incl. 8-elem wrap tails: 39 rows x 9 chunks ----
    for (int cid = tid; cid < NF * 9; cid += 256) {
        const int p  = cid / 9;
        const int s0 = (cid - 9 * p) * 8;        // 0,8,...,64
        const int e0 = s0 & 63;
        const float* gp = ebase + p * EMB;
        float4 f0 = *(const float4*)(gp + e0);
        float4 f1 = *(const float4*)(gp + ((e0 + 4) & 63));
        float  f8 = gp[(e0 + 8) & 63];
        float xv[9] = {f0.x,f0.y,f0.z,f0.w,f1.x,f1.y,f1.z,f1.w,f8};
        uint32_t us[9];
        #pragma unroll
        for (int i = 0; i < 9; ++i) {            // f32 -> bf16 RNE
            uint32_t bits = __float_as_uint(xv[i]);
            us[i] = (bits + 0x7FFFu + ((bits >> 16) & 1u)) >> 16;
        }
        uint4 dd, dw, de;
        dd.x = us[0] | (us[1] << 16); dd.y = us[2] | (us[3] << 16);   // xd
        dd.z = us[4] | (us[5] << 16); dd.w = us[6] | (us[7] << 16);
        dw.x = us[1] | (us[0] << 16); dw.y = us[3] | (us[2] << 16);   // xd swapped
        dw.z = us[5] | (us[4] << 16); dw.w = us[7] | (us[6] << 16);
        de.x = us[2] | (us[1] << 16); de.y = us[4] | (us[3] << 16);   // xs swapped
        de.z = us[6] | (us[5] << 16); de.w = us[8] | (us[7] << 16);
        *(uint4*)(lds + XD   + p * RS + s0) = dd;
        *(uint4*)(lds + XDSW + p * RS + s0) = dw;
        *(uint4*)(lds + XSSW + p * RS + s0) = de;
    }
    __syncthreads();

    // ---- B fragments (p-independent): B[m][q] = x_q[m], aligned b128 ----
    FragU Bfr[3][2];
    #pragma unroll
    for (int qi = 0; qi < 3; ++qi) {
        const int q = qi * 16 + (l & 15);
        #pragma unroll
        for (int ki = 0; ki < 2; ++ki) {
            if (q < NF) {
                const int m0 = 8 * g + 32 * ki;
                *(uint4*)Bfr[qi][ki].u = *(const uint4*)(lds + XD + q * RS + m0);
            } else {
                Bfr[qi][ki].u[0] = Bfr[qi][ki].u[1] = Bfr[qi][ki].u[2] = Bfr[qi][ki].u[3] = 0;
            }
        }
    }

    // ---- p-invariant A-gather bases: 4 runs per lane per p ----
    const int par = l & 1;
    const unsigned short* baseA = lds + (par ? XDSW : XSSW);
    const int e0 = ((l & 15) - 8 * g - 8 + par) & 63;
    const uint32_t* rp[4];
    #pragma unroll
    for (int k = 0; k < 4; ++k)
        rp[k] = (const uint32_t*)(baseA + ((e0 + 16 * k) & 63));

    auto LOADP = [&](int p, uint32_t R[4][4]) {
        const int d = p * (RS / 2);
        #pragma unroll
        for (int k = 0; k < 4; ++k)
            #pragma unroll
            for (int j = 0; j < 4; ++j)
                R[k][j] = rp[k][d + j];          // -> 2x ds_read2_b32 per run
    };

    auto COMP = [&](int p, const uint32_t R[4][4]) {
        FragU A[4];
        #pragma unroll
        for (int k = 0; k < 4; ++k)
            #pragma unroll
            for (int r = 0; r < 4; ++r) A[k].u[r] = R[k][3 - r];
        const int fb = 38 * p - (p * (p - 1)) / 2 - p - 1;   // pairIdx = fb + q
        const int q  = (l & 15);
        #pragma unroll
        for (int qi = 0; qi < 3; ++qi) {
            if (qi * 16 + 15 <= p) continue;     // tile fully q<=p: uniform skip
            f32x4 acc[4];
            #pragma unroll
            for (int t = 0; t < 4; ++t) {
                acc[t] = f32x4{0.f, 0.f, 0.f, 0.f};
                acc[t] = __builtin_amdgcn_mfma_f32_16x16x32_bf16(
                             A[t].v,           Bfr[qi][0].v, acc[t], 0, 0, 0);
                acc[t] = __builtin_amdgcn_mfma_f32_16x16x32_bf16(
                             A[(t + 2) & 3].v, Bfr[qi][1].v, acc[t], 0, 0, 0);
            }
            const int qq = qi * 16 + q;
            if (qq > p && qq < NF) {
                float* base = obase + (size_t)(unsigned)(fb + qq) * EMB + 4 * g;
                #pragma unroll
                for (int t = 0; t < 4; ++t)      // nt: stream past L2
                    __builtin_nontemporal_store(acc[t], (f32x4*)(base + 16 * t));
            }
        }
    };

    // ---- per-wave p loop (stride 4), software-pipelined 1 ahead ----
    uint32_t Ra[4][4], Rb[4][4];
    int p = w;
    if (p < NF - 1) LOADP(p, Ra);
    for (; p < NF - 1; p += 8) {
        if (p + 4 < NF - 1) LOADP(p + 4, Rb);
        COMP(p, Ra);
        if (p + 8 < NF - 1) LOADP(p + 8, Ra);
        if (p + 4 < NF - 1) COMP(p + 4, Rb);
    }
}

extern "C" void kernel_launch(void* const* d_in, const int* in_sizes, int n_in,
                              void* d_out, int out_size, void* d_ws, size_t ws_size,
                              hipStream_t stream) {
    const float* emb = (const float*)d_in[0];
    float* out = (float*)d_out;
    const int batch = in_sizes[0] / (NF * EMB);
    holo_mfma_kernel<<<batch, 256, 0, stream>>>(emb, out);
}

// Round 9
// 175.828 us; speedup vs baseline: 1.5050x; 1.5050x over previous
//
#include <hip/hip_runtime.h>

#define NF    39
#define EMB   64
#define NPAIR 741   // C(39,2)
#define RS    72    // LDS row stride in ushorts: 64 + 8 replicated tail

// LDS layout (ushort offsets). xssw at +2848 from xdsw (== 16 mod 32 banks):
// odd-lane and even-lane bank runs disjoint.
#define XD    0                 // xd[p][i]   = bf16(x[i&63])           (B-frags)
#define XDSW  2816              // xdsw[p][2j]=x[2j+1], [2j+1]=x[2j]    (A, odd c)
#define XSSW  (2816 + 2848)     // xssw[p][2j]=x[2j+2], [2j+1]=x[2j+1]  (A, even c)
#define LDSZ  (XSSW + NF * RS)  // 8472 ushorts = 16944 B

typedef short bf16x8 __attribute__((ext_vector_type(8)));
typedef float f32x4  __attribute__((ext_vector_type(4)));

union FragU { uint32_t u[4]; bf16x8 v; };

// out[b, pair(p,q), n] = sum_m x_p[(n-m)&63] * x_q[m]  (circular convolution)
// MFMA 16x16x32 bf16, D = A(circulant x_p) * B(cols x_q), C/D layout per m89.
//
// R9 = R7 structure, but each wave owns a CONTIGUOUS p-range
// {[0,5),[5,11),[11,19),[19,38)} (rows 180/183/188/190): ascending p =>
// ascending pair index => each wave's store cursor sweeps its ~47KB output
// slice strictly sequentially (R7's p-stride-4 jumped 10-40KB per iteration;
// write BW 4.5 vs 6.8 TB/s fill). R8's nt-store bypass regressed 58% -- the
// L2 half-line merge (t/t+1 pairs) is essential, keep write-back stores.
__global__ __launch_bounds__(256) void holo_mfma_kernel(
    const float* __restrict__ emb,   // [B, 39, 64]
    float* __restrict__ out)         // [B, 741, 64]
{
    __shared__ __align__(16) unsigned short lds[LDSZ];

    const int b   = blockIdx.x;
    const int tid = threadIdx.x;
    const int l   = tid & 63;
    const int w   = tid >> 6;             // wave = p-range index (0..3)
    const int g   = l >> 4;

    const float* __restrict__ ebase = emb + (size_t)b * (NF * EMB);
    float* __restrict__ obase = out + (size_t)b * (size_t)(NPAIR * EMB);

    // ---- stage 3 bf16 copies incl. 8-elem wrap tails: 39 rows x 9 chunks ----
    for (int cid = tid; cid < NF * 9; cid += 256) {
        const int p  = cid / 9;
        const int s0 = (cid - 9 * p) * 8;        // 0,8,...,64
        const int e0 = s0 & 63;
        const float* gp = ebase + p * EMB;
        float4 f0 = *(const float4*)(gp + e0);
        float4 f1 = *(const float4*)(gp + ((e0 + 4) & 63));
        float  f8 = gp[(e0 + 8) & 63];
        float xv[9] = {f0.x,f0.y,f0.z,f0.w,f1.x,f1.y,f1.z,f1.w,f8};
        uint32_t us[9];
        #pragma unroll
        for (int i = 0; i < 9; ++i) {            // f32 -> bf16 RNE
            uint32_t bits = __float_as_uint(xv[i]);
            us[i] = (bits + 0x7FFFu + ((bits >> 16) & 1u)) >> 16;
        }
        uint4 dd, dw, de;
        dd.x = us[0] | (us[1] << 16); dd.y = us[2] | (us[3] << 16);   // xd
        dd.z = us[4] | (us[5] << 16); dd.w = us[6] | (us[7] << 16);
        dw.x = us[1] | (us[0] << 16); dw.y = us[3] | (us[2] << 16);   // xd swapped
        dw.z = us[5] | (us[4] << 16); dw.w = us[7] | (us[6] << 16);
        de.x = us[2] | (us[1] << 16); de.y = us[4] | (us[3] << 16);   // xs swapped
        de.z = us[6] | (us[5] << 16); de.w = us[8] | (us[7] << 16);
        *(uint4*)(lds + XD   + p * RS + s0) = dd;
        *(uint4*)(lds + XDSW + p * RS + s0) = dw;
        *(uint4*)(lds + XSSW + p * RS + s0) = de;
    }
    __syncthreads();

    // ---- B fragments (p-independent): B[m][q] = x_q[m], aligned b128 ----
    FragU Bfr[3][2];
    #pragma unroll
    for (int qi = 0; qi < 3; ++qi) {
        const int q = qi * 16 + (l & 15);
        #pragma unroll
        for (int ki = 0; ki < 2; ++ki) {
            if (q < NF) {
                const int m0 = 8 * g + 32 * ki;
                *(uint4*)Bfr[qi][ki].u = *(const uint4*)(lds + XD + q * RS + m0);
            } else {
                Bfr[qi][ki].u[0] = Bfr[qi][ki].u[1] = Bfr[qi][ki].u[2] = Bfr[qi][ki].u[3] = 0;
            }
        }
    }

    // ---- p-invariant A-gather bases: 4 shared 16B runs per lane per p ----
    // frag(t,ki) = run[(t - 2ki) & 3]
    const int par = l & 1;
    const unsigned short* baseA = lds + (par ? XDSW : XSSW);
    const int e0 = ((l & 15) - 8 * g - 8 + par) & 63;
    const uint32_t* rp[4];
    #pragma unroll
    for (int k = 0; k < 4; ++k)
        rp[k] = (const uint32_t*)(baseA + ((e0 + 16 * k) & 63));

    auto LOADP = [&](int p, uint32_t R[4][4]) {
        const int d = p * (RS / 2);
        #pragma unroll
        for (int k = 0; k < 4; ++k)
            #pragma unroll
            for (int j = 0; j < 4; ++j)
                R[k][j] = rp[k][d + j];          // -> 2x ds_read2_b32 per run
    };

    auto COMP = [&](int p, const uint32_t R[4][4]) {
        FragU A[4];
        #pragma unroll
        for (int k = 0; k < 4; ++k)
            #pragma unroll
            for (int r = 0; r < 4; ++r) A[k].u[r] = R[k][3 - r];
        const int fb = 38 * p - (p * (p - 1)) / 2 - p - 1;   // pairIdx = fb + q
        const int q  = (l & 15);
        #pragma unroll
        for (int qi = 0; qi < 3; ++qi) {
            if (qi * 16 + 15 <= p) continue;     // tile fully q<=p: uniform skip
            f32x4 acc[4];
            #pragma unroll
            for (int t = 0; t < 4; ++t) {
                acc[t] = f32x4{0.f, 0.f, 0.f, 0.f};
                acc[t] = __builtin_amdgcn_mfma_f32_16x16x32_bf16(
                             A[t].v,           Bfr[qi][0].v, acc[t], 0, 0, 0);
                acc[t] = __builtin_amdgcn_mfma_f32_16x16x32_bf16(
                             A[(t + 2) & 3].v, Bfr[qi][1].v, acc[t], 0, 0, 0);
            }
            const int qq = qi * 16 + q;
            if (qq > p && qq < NF) {
                float* base = obase + (size_t)(unsigned)(fb + qq) * EMB + 4 * g;
                #pragma unroll
                for (int t = 0; t < 4; ++t)
                    *(f32x4*)(base + 16 * t) = acc[t];   // wave fills 4KB tile seq.
            }
        }
    };

    // ---- per-wave CONTIGUOUS p-range, software-pipelined 1 ahead ----
    const int PS0 = (w == 0) ? 0 : (w == 1) ? 5 : (w == 2) ? 11 : 19;
    const int PS1 = (w == 0) ? 5 : (w == 1) ? 11 : (w == 2) ? 19 : 38;

    uint32_t Ra[4][4], Rb[4][4];
    int p = PS0;
    LOADP(p, Ra);
    for (; p < PS1; p += 2) {
        if (p + 1 < PS1) LOADP(p + 1, Rb);
        COMP(p, Ra);
        if (p + 2 < PS1) LOADP(p + 2, Ra);
        if (p + 1 < PS1) COMP(p + 1, Rb);
    }
}

extern "C" void kernel_launch(void* const* d_in, const int* in_sizes, int n_in,
                              void* d_out, int out_size, void* d_ws, size_t ws_size,
                              hipStream_t stream) {
    const float* emb = (const float*)d_in[0];
    float* out = (float*)d_out;
    const int batch = in_sizes[0] / (NF * EMB);
    holo_mfma_kernel<<<batch, 256, 0, stream>>>(emb, out);
}

// Round 10
// 165.853 us; speedup vs baseline: 1.5955x; 1.0601x over previous
//
#include <hip/hip_runtime.h>

#define NF    39
#define EMB   64
#define NPAIR 741   // C(39,2)
#define RS    72    // LDS row stride in ushorts: 64 + 8 replicated tail

// LDS layout (ushort offsets). xssw at +2848 from xdsw (== 16 mod 32 banks):
// odd-lane and even-lane bank runs disjoint.
#define XD    0                 // xd[p][i]   = bf16(x[i&63])           (B-frags)
#define XDSW  2816              // xdsw[p][2j]=x[2j+1], [2j+1]=x[2j]    (A, odd c)
#define XSSW  (2816 + 2848)     // xssw[p][2j]=x[2j+2], [2j+1]=x[2j+1]  (A, even c)
#define LDSZ  (XSSW + NF * RS)  // 8472 ushorts = 16944 B

typedef short bf16x8 __attribute__((ext_vector_type(8)));
typedef float f32x4  __attribute__((ext_vector_type(4)));

union FragU { uint32_t u[4]; bf16x8 v; };

// out[b, pair(p,q), n] = sum_m x_p[(n-m)&63] * x_q[m]  (circular convolution)
// MFMA 16x16x32 bf16, D = A(circulant x_p) * B(cols x_q), C/D layout per m89.
//
// FINAL STRUCTURE (= R7, best measured 166.96us):
//  - one block per batch, 4 waves; wave owns p in {w, w+4, ...} and computes
//    ALL 4 n-tiles x live q-tiles of its p (full 256B output rows per wave).
//  - A-gather: n-tile t, k-slice ki needs the 16B run at element offset
//    (16t-32ki) mod 64 -> only 4 DISTINCT runs serve all 8 (t,ki) slots:
//    frag(t,ki) = run[(t-2ki)&3]. 8x ds_read2_b32 per (wave,p).
//  - pair-swapped parity LDS copies deliver rotated fragments directly
//    (A.u[r] = run dword[3-r], zero VALU).
// Store-path ledger: nt stores -58% (R8: L2 half-line merge essential);
// contiguous per-wave p-range -5% (R9); stride-4 p (this) is best.
// Write-drain-bound: ~4.5 TB/s effective on the 16-row x 64B-segment store
// pattern vs 6.7 TB/s full-line fill; compute pipes all <=20% of timeline.
__global__ __launch_bounds__(256) void holo_mfma_kernel(
    const float* __restrict__ emb,   // [B, 39, 64]
    float* __restrict__ out)         // [B, 741, 64]
{
    __shared__ __align__(16) unsigned short lds[LDSZ];

    const int b   = blockIdx.x;
    const int tid = threadIdx.x;
    const int l   = tid & 63;
    const int w   = tid >> 6;             // wave = p-stripe index (0..3)
    const int g   = l >> 4;

    const float* __restrict__ ebase = emb + (size_t)b * (NF * EMB);
    float* __restrict__ obase = out + (size_t)b * (size_t)(NPAIR * EMB);

    // ---- stage 3 bf16 copies incl. 8-elem wrap tails: 39 rows x 9 chunks ----
    for (int cid = tid; cid < NF * 9; cid += 256) {
        const int p  = cid / 9;
        const int s0 = (cid - 9 * p) * 8;        // 0,8,...,64
        const int e0 = s0 & 63;
        const float* gp = ebase + p * EMB;
        float4 f0 = *(const float4*)(gp + e0);
        float4 f1 = *(const float4*)(gp + ((e0 + 4) & 63));
        float  f8 = gp[(e0 + 8) & 63];
        float xv[9] = {f0.x,f0.y,f0.z,f0.w,f1.x,f1.y,f1.z,f1.w,f8};
        uint32_t us[9];
        #pragma unroll
        for (int i = 0; i < 9; ++i) {            // f32 -> bf16 RNE
            uint32_t bits = __float_as_uint(xv[i]);
            us[i] = (bits + 0x7FFFu + ((bits >> 16) & 1u)) >> 16;
        }
        uint4 dd, dw, de;
        dd.x = us[0] | (us[1] << 16); dd.y = us[2] | (us[3] << 16);   // xd
        dd.z = us[4] | (us[5] << 16); dd.w = us[6] | (us[7] << 16);
        dw.x = us[1] | (us[0] << 16); dw.y = us[3] | (us[2] << 16);   // xd swapped
        dw.z = us[5] | (us[4] << 16); dw.w = us[7] | (us[6] << 16);
        de.x = us[2] | (us[1] << 16); de.y = us[4] | (us[3] << 16);   // xs swapped
        de.z = us[6] | (us[5] << 16); de.w = us[8] | (us[7] << 16);
        *(uint4*)(lds + XD   + p * RS + s0) = dd;
        *(uint4*)(lds + XDSW + p * RS + s0) = dw;
        *(uint4*)(lds + XSSW + p * RS + s0) = de;
    }
    __syncthreads();

    // ---- B fragments (p-independent): B[m][q] = x_q[m], aligned b128 ----
    FragU Bfr[3][2];
    #pragma unroll
    for (int qi = 0; qi < 3; ++qi) {
        const int q = qi * 16 + (l & 15);
        #pragma unroll
        for (int ki = 0; ki < 2; ++ki) {
            if (q < NF) {
                const int m0 = 8 * g + 32 * ki;
                *(uint4*)Bfr[qi][ki].u = *(const uint4*)(lds + XD + q * RS + m0);
            } else {
                Bfr[qi][ki].u[0] = Bfr[qi][ki].u[1] = Bfr[qi][ki].u[2] = Bfr[qi][ki].u[3] = 0;
            }
        }
    }

    // ---- p-invariant A-gather bases: 4 shared 16B runs per lane per p ----
    const int par = l & 1;
    const unsigned short* baseA = lds + (par ? XDSW : XSSW);
    const int e0 = ((l & 15) - 8 * g - 8 + par) & 63;
    const uint32_t* rp[4];
    #pragma unroll
    for (int k = 0; k < 4; ++k)
        rp[k] = (const uint32_t*)(baseA + ((e0 + 16 * k) & 63));

    auto LOADP = [&](int p, uint32_t R[4][4]) {
        const int d = p * (RS / 2);
        #pragma unroll
        for (int k = 0; k < 4; ++k)
            #pragma unroll
            for (int j = 0; j < 4; ++j)
                R[k][j] = rp[k][d + j];          // -> 2x ds_read2_b32 per run
    };

    auto COMP = [&](int p, const uint32_t R[4][4]) {
        FragU A[4];
        #pragma unroll
        for (int k = 0; k < 4; ++k)
            #pragma unroll
            for (int r = 0; r < 4; ++r) A[k].u[r] = R[k][3 - r];
        const int fb = 38 * p - (p * (p - 1)) / 2 - p - 1;   // pairIdx = fb + q
        const int q  = (l & 15);
        #pragma unroll
        for (int qi = 0; qi < 3; ++qi) {
            if (qi * 16 + 15 <= p) continue;     // tile fully q<=p: uniform skip
            f32x4 acc[4];
            #pragma unroll
            for (int t = 0; t < 4; ++t) {
                acc[t] = f32x4{0.f, 0.f, 0.f, 0.f};
                acc[t] = __builtin_amdgcn_mfma_f32_16x16x32_bf16(
                             A[t].v,           Bfr[qi][0].v, acc[t], 0, 0, 0);
                acc[t] = __builtin_amdgcn_mfma_f32_16x16x32_bf16(
                             A[(t + 2) & 3].v, Bfr[qi][1].v, acc[t], 0, 0, 0);
            }
            const int qq = qi * 16 + q;
            if (qq > p && qq < NF) {
                float* base = obase + (size_t)(unsigned)(fb + qq) * EMB + 4 * g;
                #pragma unroll
                for (int t = 0; t < 4; ++t)
                    *(f32x4*)(base + 16 * t) = acc[t];   // row filled 256B by this wave
            }
        }
    };

    // ---- per-wave p loop (stride 4), software-pipelined 1 ahead ----
    uint32_t Ra[4][4], Rb[4][4];
    int p = w;
    if (p < NF - 1) LOADP(p, Ra);
    for (; p < NF - 1; p += 8) {
        if (p + 4 < NF - 1) LOADP(p + 4, Rb);
        COMP(p, Ra);
        if (p + 8 < NF - 1) LOADP(p + 8, Ra);
        if (p + 4 < NF - 1) COMP(p + 4, Rb);
    }
}

extern "C" void kernel_launch(void* const* d_in, const int* in_sizes, int n_in,
                              void* d_out, int out_size, void* d_ws, size_t ws_size,
                              hipStream_t stream) {
    const float* emb = (const float*)d_in[0];
    float* out = (float*)d_out;
    const int batch = in_sizes[0] / (NF * EMB);
    holo_mfma_kernel<<<batch, 256, 0, stream>>>(emb, out);
}